// Round 8
// baseline (481.471 us; speedup 1.0000x reference)
//
#include <hip/hip_runtime.h>

// ChainMessagePassing: out[n] = sum over edges with dst==n of x[src], over two edge lists.
// x: [N=100000, 64] fp32; indices: [2, E=3200000] (src row 0, dst row 1), int64 or int32.
//
// R11: node-major sort key. R10 post-mortem: gather flipped to VALU-bound
// (VALUBusy 73%) - the concat-run ADDP predication costs ~21 VALU ops/edge
// (16 predicated adds + 3 cmp). Fix: counting-sort key = dstlo*NT + tile
// (node-major) so each node's chunk edges form ONE contiguous ~64-edge run,
// internally tile-ordered. Each group walks its 4 nodes' runs sequentially,
// 8-deep, plain adds into a single named acc (~8 VALU ops/edge, MLP 8).
// Tile locality becomes statistical (groups sweep tiles monotonically within
// runs; uniform degrees keep blocks correlated) - FETCH expected 150-300MB.
// Prep unchanged from R10 (single-pass register-staged LDS-aggregated scatter).

static constexpr int D = 64;
static constexpr int Q = 16;          // float4 quads per row
static constexpr int NPB = 64;        // nodes per bucket
static constexpr int NPB_SHIFT = 6;
static constexpr int CHUNK = 4096;    // edges per scatter block (16/thread)
static constexpr int CH = 4096;       // edges per gather sort chunk (16 KB LDS)
static constexpr int MAXT = 32;       // max src tiles (nbins <= 2048)

// ---- index dtype sniffer: int64 nonneg <2^31 has all-zero odd dwords ----
__global__ void detect_idx_dtype(const int* __restrict__ w, int* __restrict__ flag) {
    int tid = threadIdx.x;  // one wave
    int v = w[2 * tid + 1];
    unsigned long long m = __ballot(v != 0);
    if (tid == 0) *flag = (m == 0ULL) ? 1 : 0;
}

__device__ __forceinline__ int load_idx_nt(const void* idx, long long i, int is64) {
    return is64 ? (int)__builtin_nontemporal_load(((const long long*)idx) + i)
                : __builtin_nontemporal_load(((const int*)idx) + i);
}

// ---- phase 1: bucket histogram, LDS-aggregated ----
__global__ __launch_bounds__(256) void bucket_hist_kernel(
        const void* __restrict__ up, const void* __restrict__ down,
        int* __restrict__ bcounts, const int* __restrict__ flag, int E, int NB) {
    extern __shared__ int lcnt[];
    const int is64 = *flag;
    for (int i = threadIdx.x; i < NB; i += blockDim.x) lcnt[i] = 0;
    __syncthreads();
    const long long total = 2LL * E;
    const long long stride = (long long)gridDim.x * blockDim.x;
    for (long long e = (long long)blockIdx.x * blockDim.x + threadIdx.x;
         e < total; e += stride) {
        const void* idx = up; long long ee = e;
        if (ee >= E) { idx = down; ee -= E; }
        int dst = load_idx_nt(idx, E + ee, is64);
        atomicAdd(&lcnt[dst >> NPB_SHIFT], 1);
    }
    __syncthreads();
    for (int i = threadIdx.x; i < NB; i += blockDim.x)
        if (lcnt[i]) atomicAdd(&bcounts[i], lcnt[i]);
}

// ---- phase 2: exclusive scan over NB buckets, one block ----
__global__ __launch_bounds__(1024) void scan_kernel(
        const int* __restrict__ counts, int* __restrict__ offsets,
        int* __restrict__ cursors, int NB) {
    __shared__ int sums[1024];
    const int tid = threadIdx.x;
    const int chunk = (NB + 1023) / 1024;
    const int start = tid * chunk;
    const int end = min(start + chunk, NB);
    int s = 0;
    for (int i = start; i < end; i++) s += counts[i];
    sums[tid] = s;
    __syncthreads();
    for (int off = 1; off < 1024; off <<= 1) {
        int t = (tid >= off) ? sums[tid - off] : 0;
        __syncthreads();
        sums[tid] += t;
        __syncthreads();
    }
    int run = (tid == 0) ? 0 : sums[tid - 1];
    for (int i = start; i < end; i++) {
        offsets[i] = run;
        cursors[i] = run;
        run += counts[i];
    }
    if (tid == 1023) offsets[NB] = run;
}

// ---- phase 3: scatter packed (src<<6 | dst&63) into bucket bins ----
// SINGLE global read pass: (packed,bucket) register-staged (16/thread), LDS
// histogram -> one global atomicAdd per (block,bucket) reserves a contiguous
// sub-run -> LDS-cursored writes.
__global__ __launch_bounds__(256) void bucket_scatter_kernel(
        const void* __restrict__ up, const void* __restrict__ down,
        int* __restrict__ gcursor, unsigned* __restrict__ packed,
        const int* __restrict__ flag, int E, int NB) {
    extern __shared__ int lds[];
    int* cnt = lds;        // [NB]
    int* base = lds + NB;  // [NB]
    const int is64 = *flag;
    const long long total = 2LL * E;
    const long long cs = (long long)blockIdx.x * CHUNK;
    if (cs >= total) return;
    const int m = (int)(min(total, cs + (long long)CHUNK) - cs);
    const int tid = threadIdx.x;

    for (int i = tid; i < NB; i += 256) cnt[i] = 0;
    __syncthreads();

    unsigned pr[16];
    int bkt[16];
    #pragma unroll
    for (int k = 0; k < 16; k++) {
        const int i = tid + (k << 8);
        bkt[k] = -1;
        if (i < m) {
            long long e = cs + i;
            const void* idx = up; long long ee = e;
            if (ee >= E) { idx = down; ee -= E; }
            const int src = load_idx_nt(idx, ee, is64);
            const int dst = load_idx_nt(idx, E + ee, is64);
            pr[k] = ((unsigned)src << NPB_SHIFT) | (unsigned)(dst & (NPB - 1));
            bkt[k] = dst >> NPB_SHIFT;
            atomicAdd(&cnt[bkt[k]], 1);
        }
    }
    __syncthreads();
    for (int i = tid; i < NB; i += 256) {
        int c = cnt[i];
        base[i] = c ? atomicAdd(&gcursor[i], c) : 0;
        cnt[i] = 0;  // reuse as local cursor
    }
    __syncthreads();
    #pragma unroll
    for (int k = 0; k < 16; k++) {
        if (bkt[k] >= 0) {
            int pos = base[bkt[k]] + atomicAdd(&cnt[bkt[k]], 1);
            packed[pos] = pr[k];
        }
    }
}

// ---- phase 4: per-bucket counting sort by (dstlo, src-tile) NODE-MAJOR +
// per-node contiguous-run gather. Group g (16 lanes) owns nodes 4g..4g+3;
// each node's chunk edges are ONE contiguous run (avg ~64), tile-ordered
// internally. Walk 8-deep, plain adds into one named acc per node. ----
__global__ __launch_bounds__(256) void bucket_gather_kernel(
        const float* __restrict__ x, const int* __restrict__ offsets,
        const unsigned* __restrict__ packed, float* __restrict__ out,
        int N, int shift, int NT) {
    extern __shared__ int lds[];
    unsigned* sorted = (unsigned*)lds;        // [CH]
    int* cnt = lds + CH;                      // [nbins] -> becomes cursor
    int* binoff = cnt + NT * NPB;             // [nbins+1]
    const int nbins = NT * NPB;

    const int b = blockIdx.x;
    const int tid = threadIdx.x;
    const int g = tid >> 4;   // group 0..15 (owns nodes 4g..4g+3)
    const int q = tid & 15;   // quad within row
    const int beg = offsets[b], end = offsets[b + 1];
    const float* xq = x + q * 4;

    float4 acc0 = make_float4(0.f, 0.f, 0.f, 0.f);
    float4 acc1 = acc0, acc2 = acc0, acc3 = acc0;

    for (int cs = beg; cs < end; cs += CH) {
        const int m = min(CH, end - cs);
        for (int i = tid; i < nbins; i += 256) cnt[i] = 0;
        __syncthreads();
        // hist + register stage (CH == 16*256); key = dstlo*NT + tile
        unsigned pr[16];
        #pragma unroll
        for (int k = 0; k < 16; k++) {
            const int i = tid + (k << 8);
            if (i < m) {
                unsigned p = __builtin_nontemporal_load(packed + cs + i);
                pr[k] = p;
                int key = (int)(p & (NPB - 1)) * NT + (int)(p >> (NPB_SHIFT + shift));
                atomicAdd(&cnt[key], 1);
            }
        }
        __syncthreads();
        if (tid < 64) {  // wave 0: scan over nbins; cnt becomes exclusive cursor
            const int K = (nbins + 63) >> 6;
            const int base = tid * K;
            int S = 0;
            for (int k = 0; k < K; k++) {
                int i = base + k;
                if (i < nbins) S += cnt[i];
            }
            int inc = S;
            #pragma unroll
            for (int off = 1; off < 64; off <<= 1) {
                int t = __shfl_up(inc, off, 64);
                if (tid >= off) inc += t;
            }
            int run = inc - S;  // exclusive lane offset
            for (int k = 0; k < K; k++) {
                int i = base + k;
                if (i < nbins) {
                    int c = cnt[i];
                    cnt[i] = run;
                    binoff[i + 1] = run + c;
                    run += c;
                }
            }
            if (tid == 0) binoff[0] = 0;
        }
        __syncthreads();
        #pragma unroll
        for (int k = 0; k < 16; k++) {
            const int i = tid + (k << 8);
            if (i < m) {
                unsigned p = pr[k];
                int key = (int)(p & (NPB - 1)) * NT + (int)(p >> (NPB_SHIFT + shift));
                int pos = atomicAdd(&cnt[key], 1);
                sorted[pos] = p;
            }
        }
        __syncthreads();

        // per-node contiguous runs: node dl's run = [binoff[dl*NT], binoff[(dl+1)*NT])
#define GATHER_NODE(ACC, J) do {                                               \
        const int dl = 4 * g + (J);                                            \
        const int rb = binoff[dl * NT], re = binoff[(dl + 1) * NT];            \
        int e = rb;                                                            \
        for (; e + 8 <= re; e += 8) {                                          \
            const unsigned p0 = sorted[e + 0], p1 = sorted[e + 1];             \
            const unsigned p2 = sorted[e + 2], p3 = sorted[e + 3];             \
            const unsigned p4 = sorted[e + 4], p5 = sorted[e + 5];             \
            const unsigned p6 = sorted[e + 6], p7 = sorted[e + 7];             \
            const float4 v0 = *(const float4*)(xq + ((long long)(p0 >> NPB_SHIFT)) * D); \
            const float4 v1 = *(const float4*)(xq + ((long long)(p1 >> NPB_SHIFT)) * D); \
            const float4 v2 = *(const float4*)(xq + ((long long)(p2 >> NPB_SHIFT)) * D); \
            const float4 v3 = *(const float4*)(xq + ((long long)(p3 >> NPB_SHIFT)) * D); \
            const float4 v4 = *(const float4*)(xq + ((long long)(p4 >> NPB_SHIFT)) * D); \
            const float4 v5 = *(const float4*)(xq + ((long long)(p5 >> NPB_SHIFT)) * D); \
            const float4 v6 = *(const float4*)(xq + ((long long)(p6 >> NPB_SHIFT)) * D); \
            const float4 v7 = *(const float4*)(xq + ((long long)(p7 >> NPB_SHIFT)) * D); \
            ACC.x += ((v0.x + v1.x) + (v2.x + v3.x)) + ((v4.x + v5.x) + (v6.x + v7.x)); \
            ACC.y += ((v0.y + v1.y) + (v2.y + v3.y)) + ((v4.y + v5.y) + (v6.y + v7.y)); \
            ACC.z += ((v0.z + v1.z) + (v2.z + v3.z)) + ((v4.z + v5.z) + (v6.z + v7.z)); \
            ACC.w += ((v0.w + v1.w) + (v2.w + v3.w)) + ((v4.w + v5.w) + (v6.w + v7.w)); \
        }                                                                      \
        for (; e < re; e++) {                                                  \
            const unsigned p = sorted[e];                                      \
            const float4 v = *(const float4*)(xq + ((long long)(p >> NPB_SHIFT)) * D); \
            ACC.x += v.x; ACC.y += v.y; ACC.z += v.z; ACC.w += v.w;            \
        }                                                                      \
    } while (0)

        GATHER_NODE(acc0, 0);
        GATHER_NODE(acc1, 1);
        GATHER_NODE(acc2, 2);
        GATHER_NODE(acc3, 3);
#undef GATHER_NODE
        __syncthreads();  // gather reads done before next chunk reuses LDS
    }

    const int node0 = b * NPB + 4 * g;
    if (node0 < N)
        *(float4*)(out + (long long)node0 * D + q * 4) = acc0;
    if (node0 + 1 < N)
        *(float4*)(out + (long long)(node0 + 1) * D + q * 4) = acc1;
    if (node0 + 2 < N)
        *(float4*)(out + (long long)(node0 + 2) * D + q * 4) = acc2;
    if (node0 + 3 < N)
        *(float4*)(out + (long long)(node0 + 3) * D + q * 4) = acc3;
}

// ---- fallback: direct fp32 atomics (R1), needs no workspace ----
__global__ __launch_bounds__(256) void scatter_add_kernel(
        const float* __restrict__ x, const void* __restrict__ up_idx,
        const void* __restrict__ down_idx, float* __restrict__ out,
        const int* __restrict__ dtype_flag, int num_edges) {
    const int is64 = *dtype_flag;
    const long long total = 2LL * num_edges * Q;
    const long long stride = (long long)gridDim.x * blockDim.x;
    for (long long t = (long long)blockIdx.x * blockDim.x + threadIdx.x;
         t < total; t += stride) {
        const int quad = (int)(t & (Q - 1));
        long long eg = t >> 4;
        const void* idx = up_idx;
        if (eg >= num_edges) { idx = down_idx; eg -= num_edges; }
        int src = load_idx_nt(idx, eg, is64);
        int dst = load_idx_nt(idx, num_edges + eg, is64);
        const float4 v = *(const float4*)(x + (long long)src * D + quad * 4);
        float* o = out + (long long)dst * D + quad * 4;
        unsafeAtomicAdd(o + 0, v.x);
        unsafeAtomicAdd(o + 1, v.y);
        unsafeAtomicAdd(o + 2, v.z);
        unsafeAtomicAdd(o + 3, v.w);
    }
}

extern "C" void kernel_launch(void* const* d_in, const int* in_sizes, int n_in,
                              void* d_out, int out_size, void* d_ws, size_t ws_size,
                              hipStream_t stream) {
    const float* x = (const float*)d_in[0];
    const void* up_idx = d_in[1];
    const void* down_idx = d_in[2];
    float* out = (float*)d_out;

    const int E = in_sizes[1] / 2;   // [2, E]
    const int N = out_size / D;      // [N, 64]
    const int NB = (N + NPB - 1) / NPB;
    const long long Etot = 2LL * E;

    // src tile shift: 8192 rows (2MB) preferred; coarsen so NT <= MAXT
    int shift = 13;
    while ((((long long)(N - 1) >> shift) + 1) > MAXT) shift++;
    const int NT = (int)(((long long)(N - 1) >> shift) + 1);

    // ws layout (ints): flag(64) | counts[NB] | offsets[NB+1] pad | cursors[NB] | packed[2E]
    int* ws_i = (int*)d_ws;
    int* flag = ws_i;
    int* counts = ws_i + 64;
    int* offsets = counts + NB;
    int* cursors = offsets + NB + 15;
    unsigned* packed = (unsigned*)(cursors + NB);
    const size_t ws_need = (size_t)(64 + 3LL * NB + 16 + Etot) * 4 + 64;

    detect_idx_dtype<<<1, 64, 0, stream>>>((const int*)up_idx, flag);

    if (ws_size >= ws_need && N <= (1 << 25) && Etot < (1LL << 31)) {
        hipMemsetAsync(counts, 0, (size_t)NB * sizeof(int), stream);
        bucket_hist_kernel<<<1024, 256, NB * sizeof(int), stream>>>(
            up_idx, down_idx, counts, flag, E, NB);
        scan_kernel<<<1, 1024, 0, stream>>>(counts, offsets, cursors, NB);
        const int sblocks = (int)((Etot + CHUNK - 1) / CHUNK);
        bucket_scatter_kernel<<<sblocks, 256, 2 * NB * sizeof(int), stream>>>(
            up_idx, down_idx, cursors, packed, flag, E, NB);
        const int nbins = NT * NPB;
        const size_t glds = (size_t)(CH + 2 * nbins + 4) * 4;
        bucket_gather_kernel<<<NB, 256, glds, stream>>>(
            x, offsets, packed, out, N, shift, NT);
    } else {
        hipMemsetAsync(d_out, 0, (size_t)out_size * sizeof(float), stream);
        scatter_add_kernel<<<8192, 256, 0, stream>>>(x, up_idx, down_idx, out, flag, E);
    }
}